// Round 8
// baseline (259.611 us; speedup 1.0000x reference)
//
#include <hip/hip_runtime.h>
#include <hip/hip_bf16.h>

// DilatedAttention (b=4, n=8192, d=1024, w=2048, r=4):
// 16 independent 512x512 self-attentions at d=1024 over gathered tokens
// off + 4*j per segment. alphas==1 (idx unique), so output = scatter(att).
//
// Round 8 (3 kernels): gather(x->xg,xgT bf16) ; QK+softmax fused (block owns
// full 512-col score rows; cross-wave LDS reduction; writes normalized P) ;
// PV GEMM -> nontemporal scatter store + fused zero-fill of non-idx rows.

typedef __bf16 bf16_t;
typedef __bf16 bf16x8 __attribute__((ext_vector_type(8)));
typedef float floatx4 __attribute__((ext_vector_type(4)));

#define D_MODEL 1024
#define SEG_W   2048
#define RATE    4
#define M_SUB   512          // tokens per segment after dilation (w/r)
#define NTOK    8192
#define NSEGT   16           // batch(4) * segments(4)
#define XG_ELEMS ((long)NSEGT * M_SUB * D_MODEL)
#define SM_SCALE 0.03125f    // 1/sqrt(1024), folded into exp()

__device__ __forceinline__ void gload16(const bf16_t* g, bf16_t* l) {
    __builtin_amdgcn_global_load_lds(
        (const __attribute__((address_space(1))) void*)g,
        (__attribute__((address_space(3))) void*)l, 16, 0, 0);
}

// ---------------------------------------------------------------------------
// K1: gather x[b, s*2048 + off + 4i, :] -> xg bf16 [seg][i][d]
//                                       -> xgT bf16 [seg][d][i]
// ---------------------------------------------------------------------------
__global__ __launch_bounds__(256) void gather_kernel(
    const float* __restrict__ x, const int* __restrict__ hidp,
    bf16_t* __restrict__ xg, bf16_t* __restrict__ xgT)
{
    const int off = ((hidp[0] % RATE) + RATE) % RATE;
    const int bid = blockIdx.x;
    const int seg = bid >> 7;          // 0..15
    const int rem = bid & 127;
    const int it  = rem >> 4;          // i-tile 0..7
    const int dt  = rem & 15;          // d-tile 0..15
    const int b   = seg >> 2, s = seg & 3;

    __shared__ ushort tile[64][65];

    const int t  = threadIdx.x;
    const int r  = t >> 2;             // 0..63
    const int cq = (t & 3) << 4;       // 0,16,32,48

    union U8 { bf16x8 v; ushort u[8]; };

    {
        const int  i   = it * 64 + r;
        const long tok = (long)s * SEG_W + off + 4L * i;
        const float* src = x + ((long)b * NTOK + tok) * D_MODEL + dt * 64 + cq;
        float4 f0 = ((const float4*)src)[0];
        float4 f1 = ((const float4*)src)[1];
        float4 f2 = ((const float4*)src)[2];
        float4 f3 = ((const float4*)src)[3];
        U8 lo, hi;
        lo.v[0]=(bf16_t)f0.x; lo.v[1]=(bf16_t)f0.y; lo.v[2]=(bf16_t)f0.z; lo.v[3]=(bf16_t)f0.w;
        lo.v[4]=(bf16_t)f1.x; lo.v[5]=(bf16_t)f1.y; lo.v[6]=(bf16_t)f1.z; lo.v[7]=(bf16_t)f1.w;
        hi.v[0]=(bf16_t)f2.x; hi.v[1]=(bf16_t)f2.y; hi.v[2]=(bf16_t)f2.z; hi.v[3]=(bf16_t)f2.w;
        hi.v[4]=(bf16_t)f3.x; hi.v[5]=(bf16_t)f3.y; hi.v[6]=(bf16_t)f3.z; hi.v[7]=(bf16_t)f3.w;
        bf16_t* dstg = xg + ((long)seg * M_SUB + i) * D_MODEL + dt * 64 + cq;
        *(bf16x8*)(dstg)     = lo.v;
        *(bf16x8*)(dstg + 8) = hi.v;
        #pragma unroll
        for (int j = 0; j < 8; ++j) { tile[r][cq + j] = lo.u[j]; tile[r][cq + 8 + j] = hi.u[j]; }
    }
    __syncthreads();
    {
        const int dc = r;
        const int iq = cq;
        U8 o0, o1;
        #pragma unroll
        for (int j = 0; j < 8; ++j) { o0.u[j] = tile[iq + j][dc]; o1.u[j] = tile[iq + 8 + j][dc]; }
        bf16_t* dstT = xgT + ((long)seg * D_MODEL + dt * 64 + dc) * M_SUB + it * 64 + iq;
        *(bf16x8*)(dstT)     = o0.v;
        *(bf16x8*)(dstT + 8) = o1.v;
    }
}

// ---------------------------------------------------------------------------
// K2: QK GEMM + softmax fused. Block owns FULL rows: BM=32, BN=512, BK=64.
// grid = 16 segs * 16 mt = 256 blocks, 512 threads (8 waves, 1 block/CU).
// Wave w computes cols w*64..w*64+63 (2 m-tiles x 4 n-tiles) and stages
// B keys w*64..+63 (8 gloads); waves 0-3 also stage 8 A rows each.
// Epilogue: cross-wave row max/sum via LDS, exp((s-m)*1/32), write P bf16.
// XOR chunk swizzle as before: chunk c of row r at slot c^(r&7).
// ---------------------------------------------------------------------------
__global__ __launch_bounds__(512) void qks_kernel(
    const bf16_t* __restrict__ xg, bf16_t* __restrict__ P)
{
    const int bid = blockIdx.x;
    const int seg = bid >> 4;          // 0..15
    const int mt  = bid & 15;          // 0..15 (32-row q-tile)

    const int tid  = threadIdx.x;
    const int w    = tid >> 6;          // 0..7
    const int lane = tid & 63;
    const int l16  = lane & 15;
    const int quad = lane >> 4;
    const int row8 = lane >> 3;         // 0..7
    const int cswz = ((lane & 7) ^ row8) * 8;
    const int rsw  = l16 & 7;

    __shared__ alignas(16) bf16_t As[32 * 64];    // 4 KB
    __shared__ alignas(16) bf16_t Bs[512 * 64];   // 64 KB
    __shared__ float redm[8][32];
    __shared__ float reds[8][32];

    const bf16_t* xseg = xg + (long)seg * M_SUB * D_MODEL;

    const bf16_t* gb = xseg + (long)(w * 64 + row8) * D_MODEL + cswz;
    const bf16_t* ga = xseg + (long)(mt * 32 + (w & 3) * 8 + row8) * D_MODEL + cswz;
    bf16_t* lb = &Bs[(w * 64) * 64];
    bf16_t* la = &As[((w & 3) * 8) * 64];

    floatx4 acc[2][4];
    #pragma unroll
    for (int i = 0; i < 2; ++i)
        #pragma unroll
        for (int j = 0; j < 4; ++j) acc[i][j] = (floatx4){0.f, 0.f, 0.f, 0.f};

    for (int kk = 0; kk < D_MODEL; kk += 64) {
        __syncthreads();
        #pragma unroll
        for (int rr = 0; rr < 8; ++rr)
            gload16(gb + (long)rr * 8 * D_MODEL + kk, lb + rr * 8 * 64);
        if (w < 4) gload16(ga + kk, la);
        __syncthreads();

        #pragma unroll
        for (int ks = 0; ks < 2; ++ks) {
            bf16x8 Af[2], Bf[4];
            #pragma unroll
            for (int m2 = 0; m2 < 2; ++m2) {
                const int row = m2 * 16 + l16;
                Af[m2] = *(const bf16x8*)&As[row * 64 + (((ks * 4 + quad) ^ rsw) * 8)];
            }
            #pragma unroll
            for (int n2 = 0; n2 < 4; ++n2) {
                const int key = w * 64 + n2 * 16 + l16;
                Bf[n2] = *(const bf16x8*)&Bs[key * 64 + (((ks * 4 + quad) ^ rsw) * 8)];
            }
            #pragma unroll
            for (int m2 = 0; m2 < 2; ++m2)
                #pragma unroll
                for (int n2 = 0; n2 < 4; ++n2)
                    acc[m2][n2] = __builtin_amdgcn_mfma_f32_16x16x32_bf16(Af[m2], Bf[n2], acc[m2][n2], 0, 0, 0);
        }
    }

    // ---- softmax over full rows. acc[m2][n2][rg]: row = m2*16+quad*4+rg
    // (local to this block's 32 rows), col = w*64+n2*16+l16.
    float mx[2][4];
    #pragma unroll
    for (int m2 = 0; m2 < 2; ++m2)
        #pragma unroll
        for (int rg = 0; rg < 4; ++rg) {
            float m = fmaxf(fmaxf(acc[m2][0][rg], acc[m2][1][rg]),
                            fmaxf(acc[m2][2][rg], acc[m2][3][rg]));
            #pragma unroll
            for (int d = 1; d < 16; d <<= 1) m = fmaxf(m, __shfl_xor(m, d, 64));
            mx[m2][rg] = m;
        }
    if (l16 == 0) {
        #pragma unroll
        for (int m2 = 0; m2 < 2; ++m2)
            #pragma unroll
            for (int rg = 0; rg < 4; ++rg)
                redm[w][m2 * 16 + quad * 4 + rg] = mx[m2][rg];
    }
    __syncthreads();
    float M[2][4], sm[2][4];
    #pragma unroll
    for (int m2 = 0; m2 < 2; ++m2)
        #pragma unroll
        for (int rg = 0; rg < 4; ++rg) {
            const int rr = m2 * 16 + quad * 4 + rg;
            float m = redm[0][rr];
            #pragma unroll
            for (int w2 = 1; w2 < 8; ++w2) m = fmaxf(m, redm[w2][rr]);
            M[m2][rg] = m;
            sm[m2][rg] = 0.f;
        }
    #pragma unroll
    for (int m2 = 0; m2 < 2; ++m2)
        #pragma unroll
        for (int n2 = 0; n2 < 4; ++n2)
            #pragma unroll
            for (int rg = 0; rg < 4; ++rg) {
                float p = __expf((acc[m2][n2][rg] - M[m2][rg]) * SM_SCALE);
                acc[m2][n2][rg] = p;
                sm[m2][rg] += p;
            }
    #pragma unroll
    for (int m2 = 0; m2 < 2; ++m2)
        #pragma unroll
        for (int rg = 0; rg < 4; ++rg) {
            float s2 = sm[m2][rg];
            #pragma unroll
            for (int d = 1; d < 16; d <<= 1) s2 += __shfl_xor(s2, d, 64);
            sm[m2][rg] = s2;
        }
    if (l16 == 0) {
        #pragma unroll
        for (int m2 = 0; m2 < 2; ++m2)
            #pragma unroll
            for (int rg = 0; rg < 4; ++rg)
                reds[w][m2 * 16 + quad * 4 + rg] = sm[m2][rg];
    }
    __syncthreads();

    bf16_t* Pseg = P + (long)seg * M_SUB * M_SUB;
    #pragma unroll
    for (int m2 = 0; m2 < 2; ++m2) {
        #pragma unroll
        for (int rg = 0; rg < 4; ++rg) {
            const int rr = m2 * 16 + quad * 4 + rg;
            float s2 = reds[0][rr];
            #pragma unroll
            for (int w2 = 1; w2 < 8; ++w2) s2 += reds[w2][rr];
            const float inv = 1.0f / s2;
            const int qrow = mt * 32 + rr;
            #pragma unroll
            for (int n2 = 0; n2 < 4; ++n2) {
                const int col = w * 64 + n2 * 16 + l16;
                Pseg[(long)qrow * M_SUB + col] = (bf16_t)(acc[m2][n2][rg] * inv);
            }
        }
    }
}

// ---------------------------------------------------------------------------
// K3: PV GEMM. out[tok][d] = sum_k P[q][k]*V[k][d], V^T = xgT.
// BM=BN=128, BK=64. grid = 16 segs * 4 mt * 8 nt = 512 blocks, 512 threads.
// Wave w: wr=w>>1 (32-row quarter), wc=w&1 (64-col half); 2x4 MFMA tiles.
// Epilogue: nontemporal scatter + zero-fill of 3*128 non-idx rows x 128 cols.
// ---------------------------------------------------------------------------
__global__ __launch_bounds__(512) void pv_kernel(
    const bf16_t* __restrict__ P, const bf16_t* __restrict__ xgT,
    const int* __restrict__ hidp, float* __restrict__ out)
{
    const int off = ((hidp[0] % RATE) + RATE) % RATE;
    const int bid = blockIdx.x;
    const int seg = bid >> 5;          // 0..15
    const int mt  = (bid >> 3) & 3;    // 0..3  (128-row q-tile)
    const int nt  = bid & 7;           // 0..7  (128-col d-tile)
    const int b   = seg >> 2, s = seg & 3;

    const int tid  = threadIdx.x;
    const int w    = tid >> 6;          // 0..7
    const int lane = tid & 63;
    const int l16  = lane & 15;
    const int quad = lane >> 4;
    const int wr   = w >> 1, wc = w & 1;
    const int row8 = lane >> 3;
    const int cswz = ((lane & 7) ^ row8) * 8;
    const int rsw  = l16 & 7;

    __shared__ alignas(16) bf16_t As[128 * 64];   // 16 KB
    __shared__ alignas(16) bf16_t Bs[128 * 64];   // 16 KB

    const bf16_t* Aseg = P   + (long)seg * M_SUB * M_SUB  + (long)mt * 128 * M_SUB;
    const bf16_t* Bseg = xgT + (long)seg * D_MODEL * M_SUB + (long)nt * 128 * M_SUB;

    const bf16_t* ga0 = Aseg + (long)(w * 16 + row8) * M_SUB + cswz;
    const bf16_t* ga1 = ga0 + 8 * M_SUB;
    const bf16_t* gb0 = Bseg + (long)(w * 16 + row8) * M_SUB + cswz;
    const bf16_t* gb1 = gb0 + 8 * M_SUB;
    bf16_t* la0 = &As[(w * 16 + 0) * 64];
    bf16_t* la1 = &As[(w * 16 + 8) * 64];
    bf16_t* lb0 = &Bs[(w * 16 + 0) * 64];
    bf16_t* lb1 = &Bs[(w * 16 + 8) * 64];

    floatx4 acc[2][4];
    #pragma unroll
    for (int i = 0; i < 2; ++i)
        #pragma unroll
        for (int j = 0; j < 4; ++j) acc[i][j] = (floatx4){0.f, 0.f, 0.f, 0.f};

    for (int kk = 0; kk < M_SUB; kk += 64) {
        __syncthreads();
        gload16(ga0 + kk, la0); gload16(ga1 + kk, la1);
        gload16(gb0 + kk, lb0); gload16(gb1 + kk, lb1);
        __syncthreads();

        #pragma unroll
        for (int ks = 0; ks < 2; ++ks) {
            bf16x8 Af[2], Bf[4];
            #pragma unroll
            for (int m2 = 0; m2 < 2; ++m2) {
                const int row = wr * 32 + m2 * 16 + l16;
                Af[m2] = *(const bf16x8*)&As[row * 64 + (((ks * 4 + quad) ^ rsw) * 8)];
            }
            #pragma unroll
            for (int n2 = 0; n2 < 4; ++n2) {
                const int row = wc * 64 + n2 * 16 + l16;
                Bf[n2] = *(const bf16x8*)&Bs[row * 64 + (((ks * 4 + quad) ^ rsw) * 8)];
            }
            #pragma unroll
            for (int m2 = 0; m2 < 2; ++m2)
                #pragma unroll
                for (int n2 = 0; n2 < 4; ++n2)
                    acc[m2][n2] = __builtin_amdgcn_mfma_f32_16x16x32_bf16(Af[m2], Bf[n2], acc[m2][n2], 0, 0, 0);
        }
    }

    // ---- result scatter (nontemporal: not re-read)
    float* obase = out + (long)b * NTOK * D_MODEL;
    #pragma unroll
    for (int m2 = 0; m2 < 2; ++m2) {
        const int qrow0 = mt * 128 + wr * 32 + m2 * 16 + quad * 4;
        #pragma unroll
        for (int rg = 0; rg < 4; ++rg) {
            const long tok = (long)s * SEG_W + off + 4L * (qrow0 + rg);
            float* orow = obase + tok * D_MODEL;
            #pragma unroll
            for (int n2 = 0; n2 < 4; ++n2) {
                const int d = nt * 128 + wc * 64 + n2 * 16 + l16;
                __builtin_nontemporal_store(acc[m2][n2][rg], &orow[d]);
            }
        }
    }

    // ---- fused zero-fill: 3*128 non-idx rows x this block's 128 cols
    {
        const floatx4 z = {0.f, 0.f, 0.f, 0.f};
        const int zr = tid >> 5;        // 0..15
        const int zc = tid & 31;        // float4 chunk within 128 cols
        #pragma unroll 4
        for (int p = 0; p < 24; ++p) {
            const int j = p * 16 + zr;  // 0..383
            const int q = j / 3, e = j % 3;
            const int delta = e + (e >= off ? 1 : 0);
            const long tok = (long)s * SEG_W + 4L * (mt * 128 + q) + delta;
            float* dst = obase + tok * D_MODEL + nt * 128 + zc * 4;
            __builtin_nontemporal_store(z, (floatx4*)dst);
        }
    }
}

extern "C" void kernel_launch(void* const* d_in, const int* in_sizes, int n_in,
                              void* d_out, int out_size, void* d_ws, size_t ws_size,
                              hipStream_t stream) {
    const float* x   = (const float*)d_in[0];
    const int*   hid = (const int*)d_in[1];
    float*       out = (float*)d_out;
    bf16_t* xg  = (bf16_t*)d_ws;
    bf16_t* xgT = xg + XG_ELEMS;
    bf16_t* P   = xgT + XG_ELEMS;     // total ws: 2*16.78 + 8.39 = 41.9 MB

    gather_kernel<<<dim3(2048), dim3(256), 0, stream>>>(x, hid, xg, xgT);
    qks_kernel<<<dim3(256), dim3(512), 0, stream>>>(xg, P);
    pv_kernel<<<dim3(512), dim3(512), 0, stream>>>(P, xgT, hid, out);
}